// Round 4
// baseline (476.579 us; speedup 1.0000x reference)
//
#include <hip/hip_runtime.h>

#define TILE 64

static inline size_t align256(size_t x) { return (x + 255) & ~(size_t)255; }

// ---------------------------------------------------------------------------
// K1: HT slab layout HT[p][n][bl], p = b/64, bl = b%64.
// HT = pred_p*p_scale + p_mean + elev, transposed via LDS tile.
// ---------------------------------------------------------------------------
__global__ void k_build_ht(const float* __restrict__ pred_p,
                           const float* __restrict__ p_scale,
                           const float* __restrict__ p_mean,
                           const float* __restrict__ elev,
                           float* __restrict__ HT,
                           int N) {
    __shared__ float tile[TILE][TILE + 1];
    const int n0 = blockIdx.x * TILE;
    const int p  = blockIdx.y;           // batch slab
    const int b0 = p * TILE;
    const int tn = threadIdx.x % TILE;
    const int tw = threadIdx.x / TILE;

    const int n = n0 + tn;
    float sc = 0.f, mn = 0.f, el = 0.f;
    if (n < N) { sc = p_scale[n]; mn = p_mean[n]; el = elev[n]; }

    #pragma unroll
    for (int i = 0; i < TILE / 4; ++i) {
        const int bl = i * 4 + tw;
        float v = 0.f;
        if (n < N) v = pred_p[(size_t)(b0 + bl) * N + n] * sc + mn + el;
        tile[tn][bl] = v;
    }
    __syncthreads();
    #pragma unroll
    for (int i = 0; i < TILE / 4; ++i) {
        const int nl = i * 4 + tw;
        const int nn = n0 + nl;
        if (nn < N) HT[((size_t)p * N + nn) * TILE + tn] = tile[nl][tn];
    }
}

// ---------------------------------------------------------------------------
// CSR build: histogram -> block scan -> top scan -> final scan -> fill
// incidence entry: (edge<<1)|1 for dst (+Q), (edge<<1) for src (-Q)
// ---------------------------------------------------------------------------
__global__ void k_hist(const int* __restrict__ nodes, int* __restrict__ deg, int M) {
    const int i = blockIdx.x * 256 + threadIdx.x;
    if (i < M) atomicAdd(&deg[nodes[i]], 1);
}

__global__ void k_scan1(const int* __restrict__ deg, int* __restrict__ bsum, int N) {
    __shared__ int s[256];
    const int i = blockIdx.x * 256 + threadIdx.x;
    s[threadIdx.x] = (i < N) ? deg[i] : 0;
    __syncthreads();
    #pragma unroll
    for (int off = 128; off >= 1; off >>= 1) {
        if (threadIdx.x < off) s[threadIdx.x] += s[threadIdx.x + off];
        __syncthreads();
    }
    if (threadIdx.x == 0) bsum[blockIdx.x] = s[0];
}

__global__ void k_scan2(int* __restrict__ bsum, int nb) {   // nb <= 256, 1 block
    __shared__ int s[256];
    const int t = threadIdx.x;
    const int v = (t < nb) ? bsum[t] : 0;
    s[t] = v;
    __syncthreads();
    #pragma unroll
    for (int off = 1; off < 256; off <<= 1) {
        const int tmp = (t >= off) ? s[t - off] : 0;
        __syncthreads();
        s[t] += tmp;
        __syncthreads();
    }
    if (t < nb) bsum[t] = s[t] - v;      // exclusive
}

__global__ void k_scan3(const int* __restrict__ deg, const int* __restrict__ bsum,
                        int* __restrict__ offsets, int* __restrict__ cursor, int N) {
    __shared__ int s[256];
    const int t = threadIdx.x;
    const int i = blockIdx.x * 256 + t;
    const int v = (i < N) ? deg[i] : 0;
    s[t] = v;
    __syncthreads();
    #pragma unroll
    for (int off = 1; off < 256; off <<= 1) {
        const int tmp = (t >= off) ? s[t - off] : 0;
        __syncthreads();
        s[t] += tmp;
        __syncthreads();
    }
    const int excl = s[t] - v + bsum[blockIdx.x];
    if (i < N) { offsets[i] = excl; cursor[i] = excl; }
    if (i == N - 1) offsets[N] = excl + v;   // total = 2E
}

__global__ void k_fill(const int* __restrict__ esrc, const int* __restrict__ edst,
                       int* __restrict__ cursor, int* __restrict__ inc, int E) {
    const int e = blockIdx.x * 256 + threadIdx.x;
    if (e < E) {
        const int s = esrc[e];
        const int ps = atomicAdd(&cursor[s], 1);
        inc[ps] = (e << 1);            // outflow: -Q
        const int d = edst[e];
        const int pd = atomicAdd(&cursor[d], 1);
        inc[pd] = (e << 1) | 1;        // inflow: +Q
    }
}

// ---------------------------------------------------------------------------
// K2 (per batch slab): Q from pred_f -> stream to QT[E][64]; head loss via
// HT-slab gathers.  No atomics except one f64 per block.
// ---------------------------------------------------------------------------
__global__ void k_edges(const float* __restrict__ pred_f,
                        const float* __restrict__ f_scale,
                        const float* __restrict__ f_mean,
                        const float* __restrict__ Rcoef,
                        const int* __restrict__ esrc,
                        const int* __restrict__ edst,
                        const float* __restrict__ HTp,   // slab [N][64]
                        float* __restrict__ QT,          // [E][64]
                        double* __restrict__ head_accum,
                        int b0, int E) {
    __shared__ float qt[TILE][TILE + 1];
    const int e0 = blockIdx.x * TILE;
    const int te = threadIdx.x % TILE;
    const int tw = threadIdx.x / TILE;

    const int e = e0 + te;
    const float fs = f_scale[e];
    const float fm = f_mean[e];
    #pragma unroll
    for (int i = 0; i < TILE / 4; ++i) {
        const int bl = i * 4 + tw;
        qt[te][bl] = pred_f[(size_t)(b0 + bl) * E + e] * fs + fm;
    }
    __syncthreads();

    double head = 0.0;
    const int bl = te;
    #pragma unroll
    for (int j = 0; j < TILE / 4; ++j) {
        const int el = tw * 16 + j;      // wave-uniform edge
        const int ee = e0 + el;
        const int s = esrc[ee];
        const int d = edst[ee];
        const float q = qt[el][bl];

        QT[(size_t)ee * TILE + bl] = q;

        const float hs = HTp[(size_t)s * TILE + bl];
        const float hd = HTp[(size_t)d * TILE + bl];
        const float aq = fabsf(q);
        const float pw = exp2f(0.852f * __log2f(aq));   // |q|^0.852
        const float fr = Rcoef[ee] * q * pw;
        const float t = (hs - hd) - fr;
        head += (double)t * (double)t;
    }

    #pragma unroll
    for (int off = 32; off >= 1; off >>= 1)
        head += __shfl_down(head, off, 64);
    __shared__ double wsum[4];
    if ((threadIdx.x & 63) == 0) wsum[threadIdx.x >> 6] = head;
    __syncthreads();
    if (threadIdx.x == 0)
        atomicAdd(head_accum, wsum[0] + wsum[1] + wsum[2] + wsum[3]);
}

// ---------------------------------------------------------------------------
// K3 (per batch slab): node-centric q_net from CSR + QT rows; fused mass loss
// with transposed true_d read.
// ---------------------------------------------------------------------------
__global__ void k_node(const float* __restrict__ true_d,
                       const float* __restrict__ d_scale,
                       const float* __restrict__ d_mean,
                       const float* __restrict__ QT,     // [E][64]
                       const int* __restrict__ offsets,
                       const int* __restrict__ inc,
                       double* __restrict__ mass_accum,
                       int b0, int N) {
    __shared__ float dt[TILE][TILE + 1];
    const int n0 = blockIdx.x * TILE;
    const int tn = threadIdx.x % TILE;
    const int tw = threadIdx.x / TILE;

    const int n = n0 + tn;
    float sc = 0.f, mn = 0.f;
    if (n < N) { sc = d_scale[n]; mn = d_mean[n]; }
    #pragma unroll
    for (int i = 0; i < TILE / 4; ++i) {
        const int bl = i * 4 + tw;
        float v = 0.f;
        if (n < N) v = true_d[(size_t)(b0 + bl) * N + n] * sc + mn;
        dt[tn][bl] = v;
    }
    __syncthreads();

    double m = 0.0;
    const int bl = tn;
    #pragma unroll
    for (int j = 0; j < TILE / 4; ++j) {
        const int nl = tw * 16 + j;      // wave-uniform node
        const int nn = n0 + nl;
        if (nn < N) {
            const int beg = offsets[nn];
            const int end = offsets[nn + 1];
            float qn = 0.f;
            for (int k = beg; k < end; ++k) {     // wave-uniform bounds
                const int ic = inc[k];            // scalar broadcast
                const float q = QT[(size_t)(ic >> 1) * TILE + bl];
                qn += (ic & 1) ? q : -q;
            }
            const float t = qn - dt[nl][bl];
            m += (double)t * (double)t;
        }
    }

    #pragma unroll
    for (int off = 32; off >= 1; off >>= 1)
        m += __shfl_down(m, off, 64);
    __shared__ double wsum[4];
    if ((threadIdx.x & 63) == 0) wsum[threadIdx.x >> 6] = m;
    __syncthreads();
    if (threadIdx.x == 0)
        atomicAdd(mass_accum, wsum[0] + wsum[1] + wsum[2] + wsum[3]);
}

// ---------------------------------------------------------------------------
__global__ void k_final(const double* __restrict__ accum,
                        float* __restrict__ out,
                        double inv_mass_count, double inv_head_count) {
    out[0] = (float)(accum[0] * inv_mass_count);
    out[1] = (float)(accum[1] * inv_head_count);
}

extern "C" void kernel_launch(void* const* d_in, const int* in_sizes, int n_in,
                              void* d_out, int out_size, void* d_ws, size_t ws_size,
                              hipStream_t stream) {
    const float* pred_p  = (const float*)d_in[0];
    const float* pred_f  = (const float*)d_in[1];
    const float* true_d  = (const float*)d_in[2];
    const float* p_mean  = (const float*)d_in[3];
    const float* p_scale = (const float*)d_in[4];
    const float* f_mean  = (const float*)d_in[5];
    const float* f_scale = (const float*)d_in[6];
    const float* d_mean  = (const float*)d_in[7];
    const float* d_scale = (const float*)d_in[8];
    const float* elev    = (const float*)d_in[9];
    const float* Rcoef   = (const float*)d_in[10];
    const int*   eidx    = (const int*)d_in[11];

    const int N = in_sizes[3];              // 50000
    const int E = in_sizes[10];             // 128000
    const int B = in_sizes[0] / N;          // 256
    const int NP = B / TILE;                // 4 batch slabs

    const int* esrc = eidx;
    const int* edst = eidx + E;

    // ---- workspace layout (aligned 256B) ----
    char* ws = (char*)d_ws;
    size_t off = 0;
    float* HT = (float*)(ws + off);  off = align256(off + (size_t)NP * N * TILE * 4);
    float* QT = (float*)(ws + off);  off = align256(off + (size_t)E * TILE * 4);
    int* inc      = (int*)(ws + off); off = align256(off + (size_t)2 * E * 4);
    int* offsets  = (int*)(ws + off); off = align256(off + (size_t)(N + 1) * 4);
    int* cursor   = (int*)(ws + off); off = align256(off + (size_t)N * 4);
    // zeroed region starts here:
    const size_t zero_beg = off;
    int* deg      = (int*)(ws + off); off = align256(off + (size_t)N * 4);
    int* bsum     = (int*)(ws + off); off = align256(off + 256 * 4);
    double* accum = (double*)(ws + off); off += 2 * sizeof(double);
    const size_t zero_len = off - zero_beg;

    hipMemsetAsync(ws + zero_beg, 0, zero_len, stream);

    const int gn = (N + TILE - 1) / TILE;   // 782
    const int ge = E / TILE;                // 2000
    const int nb = (N + 255) / 256;         // 196 scan blocks

    k_build_ht<<<dim3(gn, NP), 256, 0, stream>>>(pred_p, p_scale, p_mean, elev,
                                                 HT, N);
    k_hist <<<(2 * E + 255) / 256, 256, 0, stream>>>(eidx, deg, 2 * E);
    k_scan1<<<nb, 256, 0, stream>>>(deg, bsum, N);
    k_scan2<<<1, 256, 0, stream>>>(bsum, nb);
    k_scan3<<<nb, 256, 0, stream>>>(deg, bsum, offsets, cursor, N);
    k_fill <<<(E + 255) / 256, 256, 0, stream>>>(esrc, edst, cursor, inc, E);

    for (int p = 0; p < NP; ++p) {
        const int b0 = p * TILE;
        const float* HTp = HT + (size_t)p * N * TILE;
        k_edges<<<ge, 256, 0, stream>>>(pred_f, f_scale, f_mean, Rcoef,
                                        esrc, edst, HTp, QT,
                                        accum + 1, b0, E);
        k_node <<<gn, 256, 0, stream>>>(true_d, d_scale, d_mean, QT,
                                        offsets, inc,
                                        accum + 0, b0, N);
    }

    k_final<<<1, 1, 0, stream>>>(accum, (float*)d_out,
                                 1.0 / ((double)B * (double)N),
                                 1.0 / ((double)B * (double)E));
}